// Round 11
// baseline (391.740 us; speedup 1.0000x reference)
//
#include <hip/hip_runtime.h>

#define ATT_SLOPE 0.2f
#define ACT_SLOPE 0.01f

typedef _Float16 half8  __attribute__((ext_vector_type(8)));
typedef _Float16 half2v __attribute__((ext_vector_type(2)));
typedef float    floatx4 __attribute__((ext_vector_type(4)));

#if defined(__has_builtin)
#if __has_builtin(__builtin_amdgcn_fdot2)
#define HAVE_FDOT2 1
#endif
#endif

__device__ __forceinline__ float lrelu(float v, float s) {
    return fmaxf(v, v * s);
}

__device__ __forceinline__ half2v lrelu2(half2v m) {
    half2v t = m * (_Float16)ATT_SLOPE;
    return __builtin_elementwise_max(m, t);
}

__device__ __forceinline__ float dot2(half2v a, half2v b, float c) {
#ifdef HAVE_FDOT2
    return __builtin_amdgcn_fdot2(a, b, c, false);
#else
    return c + (float)a[0] * (float)b[0] + (float)a[1] * (float)b[1];
#endif
}

// ---------------- CSR build (edges grouped by dst, self loops appended) ----------------

// count + rank within dst (atomic order is non-deterministic; rows are sorted afterwards
// by k_sort_rows, which makes the final CSR a pure function of the input)
__global__ __launch_bounds__(256) void k_count_rank(const int* __restrict__ ei, int E, int N,
                                                    int* __restrict__ deg,
                                                    int* __restrict__ rank) {
    int i = blockIdx.x * 256 + threadIdx.x;
    int total = E + N;
    if (i >= total) return;
    int dst = (i < E) ? ei[E + i] : (i - E);
    rank[i] = atomicAdd(&deg[dst], 1);
}

__global__ __launch_bounds__(256) void k_scan_block(const int* __restrict__ deg, int n,
                                                    int* __restrict__ rp1, int* __restrict__ bsum) {
    __shared__ int s[256];
    int tid = threadIdx.x;
    int i = blockIdx.x * 256 + tid;
    s[tid] = (i < n) ? deg[i] : 0;
    __syncthreads();
    for (int off = 1; off < 256; off <<= 1) {
        int t = (tid >= off) ? s[tid - off] : 0;
        __syncthreads();
        s[tid] += t;
        __syncthreads();
    }
    if (i < n) rp1[i] = s[tid];
    if (tid == 255) bsum[blockIdx.x] = s[255];
}

__global__ __launch_bounds__(256) void k_scan_bsum(const int* __restrict__ bsum, int nb,
                                                   int* __restrict__ boff) {
    __shared__ int s[256];
    int tid = threadIdx.x;
    s[tid] = (tid < nb) ? bsum[tid] : 0;
    __syncthreads();
    for (int off = 1; off < 256; off <<= 1) {
        int t = (tid >= off) ? s[tid - off] : 0;
        __syncthreads();
        s[tid] += t;
        __syncthreads();
    }
    if (tid < nb) boff[tid] = (tid > 0) ? s[tid - 1] : 0;
}

__global__ __launch_bounds__(256) void k_scan_add(int* __restrict__ rowptr,
                                                  const int* __restrict__ boff, int n) {
    int i = blockIdx.x * 256 + threadIdx.x;
    if (i < n) rowptr[i + 1] += boff[blockIdx.x];
    if (i == 0) rowptr[0] = 0;
}

// XCD-partitioned owner-writes scatter (no cross-XCD partial-line write amplification).
__global__ __launch_bounds__(256) void k_scatter(const int* __restrict__ ei, int E, int N,
                                                 const int* __restrict__ rowptr,
                                                 const int* __restrict__ rank,
                                                 int* __restrict__ adj) {
    const int T = E + N;
    const int part = blockIdx.x & 7;
    const int rng = (N + 7) / 8;
    const int lo = part * rng, hi = min(N, lo + rng);
    const int nb = gridDim.x >> 3;
    for (int base = (int)(blockIdx.x >> 3) * 256; base < T; base += nb * 256) {
        int i = base + threadIdx.x;
        if (i >= T) continue;
        int dst = (i < E) ? ei[E + i] : (i - E);
        if (dst >= lo && dst < hi) {
            int src = (i < E) ? ei[i] : dst;
            adj[rowptr[dst] + rank[i]] = src;
        }
    }
}

// Sort each CSR row ascending (insertion sort; rows are ~17 long, L1-resident).
// Determinism: after this, adj is independent of atomic scatter ordering, so every
// launch produces bit-identical outputs (required by the replay tripwire).
__global__ __launch_bounds__(256) void k_sort_rows(const int* __restrict__ rowptr,
                                                   int* __restrict__ adj, int n) {
    int v = blockIdx.x * 256 + threadIdx.x;
    if (v >= n) return;
    int s = rowptr[v], e = rowptr[v + 1];
    for (int i = s + 1; i < e; ++i) {
        int key = adj[i];
        int j = i - 1;
        while (j >= s && adj[j] > key) { adj[j + 1] = adj[j]; --j; }
        adj[j + 1] = key;
    }
}

// ---------------- weight hi/lo fp16 split encode (all four matrices, one launch) ------------

__global__ __launch_bounds__(256) void k_encode_w(const float* __restrict__ w1l,
                                                  const float* __restrict__ w1r,
                                                  const float* __restrict__ w2l,
                                                  const float* __restrict__ w2r,
                                                  _Float16* __restrict__ W1h,
                                                  _Float16* __restrict__ W1lo,
                                                  _Float16* __restrict__ W2h,
                                                  _Float16* __restrict__ W2lo) {
    int i = blockIdx.x * 256 + threadIdx.x;   // 0 .. 49151
    if (i >= 49152) return;
    float v;
    _Float16 *ph, *pl;
    int idx;
    if (i < 32768) {
        idx = i;
        v = (i < 16384) ? w1l[i] : w1r[i - 16384];
        ph = W1h; pl = W1lo;
    } else {
        int j = i - 32768;
        idx = j;
        v = (j < 8192) ? w2l[j] : w2r[j - 8192];
        ph = W2h; pl = W2lo;
    }
    _Float16 h = (_Float16)v;
    ph[idx] = h;
    pl[idx] = (_Float16)(v - (float)h);
}

// ---------------- MFMA split-f16 dual linear, LDS-staged W, fp16 out ----------------

template <int COUT, bool IN_F32>
__global__ __launch_bounds__(512) void gemm_mfma(const float* __restrict__ Af,
                                                 const _Float16* __restrict__ Ahi,
                                                 const _Float16* __restrict__ Alo, int n_rows,
                                                 const _Float16* __restrict__ Whi,
                                                 const _Float16* __restrict__ Wlo,
                                                 const float* __restrict__ B0,
                                                 const float* __restrict__ B1,
                                                 _Float16* __restrict__ out) {
    constexpr int NT = COUT / 16;
    constexpr int WS = 40;                      // 32 + 8 pad (16B-aligned)
    __shared__ _Float16 sWh[COUT][WS];
    __shared__ _Float16 sWl[COUT][WS];
    const int tid = threadIdx.x;
    const int lane = tid & 63, wv = tid >> 6;
    const int m = lane & 15, q = lane >> 4;
    const long row0 = ((long)blockIdx.x * 8 + wv) * 16;
    const bool active = row0 < n_rows;          // wave-uniform (n_rows % 16 == 0)
    const long arow = row0 + m;

    floatx4 acc[NT] = {};
    for (int kk = 0; kk < 128; kk += 32) {
        __syncthreads();                        // protect previous phase's reads
        for (int t = tid; t < COUT * 4; t += 512) {
            int c = t >> 2, ch = t & 3;
            *(half8*)&sWh[c][ch * 8] = *(const half8*)&Whi[(size_t)c * 128 + kk + ch * 8];
            *(half8*)&sWl[c][ch * 8] = *(const half8*)&Wlo[(size_t)c * 128 + kk + ch * 8];
        }
        __syncthreads();
        if (active) {
            half8 ah, al;
            if constexpr (IN_F32) {
                float4 a0 = *(const float4*)&Af[(size_t)arow * 128 + kk + q * 8];
                float4 a1 = *(const float4*)&Af[(size_t)arow * 128 + kk + q * 8 + 4];
                float av[8] = {a0.x, a0.y, a0.z, a0.w, a1.x, a1.y, a1.z, a1.w};
                #pragma unroll
                for (int x = 0; x < 8; ++x) {
                    ah[x] = (_Float16)av[x];
                    al[x] = (_Float16)(av[x] - (float)ah[x]);
                }
            } else {
                ah = *(const half8*)&Ahi[(size_t)arow * 128 + kk + q * 8];
                al = *(const half8*)&Alo[(size_t)arow * 128 + kk + q * 8];
            }
            #pragma unroll
            for (int nt = 0; nt < NT; ++nt) {
                half8 bh = *(const half8*)&sWh[nt * 16 + m][q * 8];
                half8 bl = *(const half8*)&sWl[nt * 16 + m][q * 8];
                acc[nt] = __builtin_amdgcn_mfma_f32_16x16x32_f16(ah, bh, acc[nt], 0, 0, 0);
                acc[nt] = __builtin_amdgcn_mfma_f32_16x16x32_f16(al, bh, acc[nt], 0, 0, 0);
                acc[nt] = __builtin_amdgcn_mfma_f32_16x16x32_f16(ah, bl, acc[nt], 0, 0, 0);
            }
        }
    }
    if (active) {
        // C/D layout: col = lane&15, row = (lane>>4)*4 + reg
        #pragma unroll
        for (int nt = 0; nt < NT; ++nt) {
            int col = nt * 16 + m;
            float b = (col < COUT / 2) ? B0[col] : B1[col - COUT / 2];
            #pragma unroll
            for (int r = 0; r < 4; ++r) {
                long grow = row0 + q * 4 + r;
                out[(size_t)grow * COUT + col] = (_Float16)(acc[nt][r] + b);
            }
        }
    }
}

// ---------------- fused GATv2 conv1 edge phase (heads=2, ch=64) ----------------
// Chunk = 16 edges, 4 lanes/edge (each 32 of 128 ch); quarter-logits via shfl_xor(16).

__global__ __launch_bounds__(256) void conv1_fused(const _Float16* __restrict__ buf,
                                                   const int* __restrict__ rowptr,
                                                   const int* __restrict__ adj,
                                                   const float* __restrict__ att,   // [128]
                                                   const float* __restrict__ bias,  // [128]
                                                   _Float16* __restrict__ h1hi,
                                                   _Float16* __restrict__ h1lo, int n) {
    __shared__ _Float16 sxl[4][16][136];   // 272B row stride, 16B-aligned
    __shared__ _Float16 sxr[4][128];
    __shared__ float    sw[4][2][16];
    __shared__ _Float16 satt[128];
    const int tid = threadIdx.x, lane = tid & 63, wv = tid >> 6;
    if (tid < 128) satt[tid] = (_Float16)att[tid];
    __syncthreads();                        // all threads reach; no block barriers after this
    int node = blockIdx.x * 4 + wv;
    if (node >= n) return;

    const int jlane = lane & 15;           // edge slot within chunk
    const int grp = lane >> 4;             // channel quarter 0..3 (0,1->head0; 2,3->head1)
    const int chq = grp * 32;
    const int head = grp >> 1;
    const int wselg = lane >> 5;           // phase-B head for channels lane*2 (0..127)
    if (lane < 16)
        *(half8*)&sxr[wv][lane * 8] = *(const half8*)&buf[(size_t)node * 256 + 128 + lane * 8];
    asm volatile("s_waitcnt lgkmcnt(0)" ::: "memory");

    const int s = rowptr[node], e = rowptr[node + 1];
    float2 accA = {0.f, 0.f}, accB = {0.f, 0.f};
    float denA = 0.f, denB = 0.f;
    for (int c0 = s; c0 < e; c0 += 16) {
        const int cnt = min(16, e - c0);
        float sacc0 = 0.f, sacc1 = 0.f;
        if (jlane < cnt) {
            int src = adj[c0 + jlane];
            const _Float16* xlp = &buf[(size_t)src * 256 + chq];
            #pragma unroll
            for (int k = 0; k < 4; ++k) {
                half8 l = *(const half8*)&xlp[k * 8];
                half8 r = *(const half8*)&sxr[wv][chq + k * 8];
                half8 a = *(const half8*)&satt[chq + k * 8];
                *(half8*)&sxl[wv][jlane][chq + k * 8] = l;
                float* sp = (k & 1) ? &sacc1 : &sacc0;
                #pragma unroll
                for (int p = 0; p < 4; ++p) {
                    half2v lp = {l[2 * p], l[2 * p + 1]};
                    half2v rp = {r[2 * p], r[2 * p + 1]};
                    half2v ap = {a[2 * p], a[2 * p + 1]};
                    *sp = dot2(lrelu2(lp + rp), ap, *sp);
                }
            }
        }
        float sacc = sacc0 + sacc1;
        float efull = sacc + __shfl_xor(sacc, 16);   // combine the two quarters of this head
        if ((grp & 1) == 0 && jlane < cnt) sw[wv][head][jlane] = __expf(efull);
        asm volatile("s_waitcnt lgkmcnt(0)" ::: "memory");
        // phase B: lane -> channels (2*lane, 2*lane+1); its head's weights; 2-way unroll
        int j = 0;
        for (; j + 1 < cnt; j += 2) {
            float w0 = sw[wv][wselg][j], w1 = sw[wv][wselg][j + 1];
            half2v v0 = *(const half2v*)&sxl[wv][j][lane * 2];
            half2v v1 = *(const half2v*)&sxl[wv][j + 1][lane * 2];
            accA.x += w0 * (float)v0[0]; accA.y += w0 * (float)v0[1]; denA += w0;
            accB.x += w1 * (float)v1[0]; accB.y += w1 * (float)v1[1]; denB += w1;
        }
        if (j < cnt) {
            float w0 = sw[wv][wselg][j];
            half2v v0 = *(const half2v*)&sxl[wv][j][lane * 2];
            accA.x += w0 * (float)v0[0]; accA.y += w0 * (float)v0[1]; denA += w0;
        }
        asm volatile("s_waitcnt lgkmcnt(0)" ::: "memory");  // drain reads before next overwrite
    }
    float inv = 1.f / (denA + denB);
    float2 b = *(const float2*)&bias[lane * 2];
    float ox = lrelu((accA.x + accB.x) * inv + b.x, ACT_SLOPE);
    float oy = lrelu((accA.y + accB.y) * inv + b.y, ACT_SLOPE);
    half2v hv, lv;
    hv[0] = (_Float16)ox; lv[0] = (_Float16)(ox - (float)hv[0]);
    hv[1] = (_Float16)oy; lv[1] = (_Float16)(oy - (float)hv[1]);
    *(half2v*)&h1hi[(size_t)node * 128 + lane * 2] = hv;
    *(half2v*)&h1lo[(size_t)node * 128 + lane * 2] = lv;
}

// ---------------- fused GATv2 conv2 edge phase (heads=1, ch=64) ----------------

__global__ __launch_bounds__(256) void conv2_fused(const _Float16* __restrict__ buf,
                                                   const int* __restrict__ rowptr,
                                                   const int* __restrict__ adj,
                                                   const float* __restrict__ att,   // [64]
                                                   const float* __restrict__ bias,  // [64]
                                                   float* __restrict__ h2, int n) {
    __shared__ _Float16 sxl[4][16][72];    // 144B row stride, 16B-aligned
    __shared__ _Float16 sxr[4][64];
    __shared__ float    sw[4][16];
    __shared__ _Float16 satt[64];
    const int tid = threadIdx.x, lane = tid & 63, wv = tid >> 6;
    if (tid < 64) satt[tid] = (_Float16)att[tid];
    __syncthreads();
    int node = blockIdx.x * 4 + wv;
    if (node >= n) return;

    const int jlane = lane & 15;
    const int grp = lane >> 4;             // channel quarter 0..3 (16 ch each)
    const int chq = grp * 16;
    if (lane < 8)
        *(half8*)&sxr[wv][lane * 8] = *(const half8*)&buf[(size_t)node * 128 + 64 + lane * 8];
    asm volatile("s_waitcnt lgkmcnt(0)" ::: "memory");

    const int s = rowptr[node], e = rowptr[node + 1];
    float accA = 0.f, accB = 0.f, denA = 0.f, denB = 0.f;
    for (int c0 = s; c0 < e; c0 += 16) {
        const int cnt = min(16, e - c0);
        float sacc = 0.f;
        if (jlane < cnt) {
            int src = adj[c0 + jlane];
            const _Float16* xlp = &buf[(size_t)src * 128 + chq];
            #pragma unroll
            for (int k = 0; k < 2; ++k) {
                half8 l = *(const half8*)&xlp[k * 8];
                half8 r = *(const half8*)&sxr[wv][chq + k * 8];
                half8 a = *(const half8*)&satt[chq + k * 8];
                *(half8*)&sxl[wv][jlane][chq + k * 8] = l;
                #pragma unroll
                for (int p = 0; p < 4; ++p) {
                    half2v lp = {l[2 * p], l[2 * p + 1]};
                    half2v rp = {r[2 * p], r[2 * p + 1]};
                    half2v ap = {a[2 * p], a[2 * p + 1]};
                    sacc = dot2(lrelu2(lp + rp), ap, sacc);
                }
            }
        }
        float s1 = sacc + __shfl_xor(sacc, 16);
        float efull = s1 + __shfl_xor(s1, 32);
        if (grp == 0 && jlane < cnt) sw[wv][jlane] = __expf(efull);
        asm volatile("s_waitcnt lgkmcnt(0)" ::: "memory");
        int j = 0;
        for (; j + 1 < cnt; j += 2) {
            float w0 = sw[wv][j], w1 = sw[wv][j + 1];
            accA += w0 * (float)sxl[wv][j][lane];     denA += w0;
            accB += w1 * (float)sxl[wv][j + 1][lane]; denB += w1;
        }
        if (j < cnt) {
            float w0 = sw[wv][j];
            accA += w0 * (float)sxl[wv][j][lane];
            denA += w0;
        }
        asm volatile("s_waitcnt lgkmcnt(0)" ::: "memory");
    }
    h2[(size_t)node * 64 + lane] = lrelu((accA + accB) / (denA + denB) + bias[lane], ACT_SLOPE);
}

// ---------------- global mean pool (batch sorted) + fc1 + lrelu + fc2 ----------------

__device__ __forceinline__ int lower_bound(const int* a, int n, int v) {
    int lo = 0, hi = n;
    while (lo < hi) { int mid = (lo + hi) >> 1; if (a[mid] < v) lo = mid + 1; else hi = mid; }
    return lo;
}

__global__ __launch_bounds__(256) void pool_mlp(const float* __restrict__ h2,   // [N,64]
                                                const int* __restrict__ batch,  // [N] sorted
                                                const float* __restrict__ fc1_w,
                                                const float* __restrict__ fc1_b,
                                                const float* __restrict__ fc2_w,
                                                const float* __restrict__ fc2_b,
                                                float* __restrict__ out, int n) {
    const int g = blockIdx.x;
    const int tid = threadIdx.x;
    const int c = tid & 63, q = tid >> 6;
    __shared__ float partial[4][64];
    __shared__ float pooled[64];
    __shared__ float hmid[64];

    int lo = lower_bound(batch, n, g);
    int hi = lower_bound(batch, n, g + 1);

    float sum = 0.f;
    for (int i = lo + q; i < hi; i += 4) sum += h2[(size_t)i * 64 + c];
    partial[q][c] = sum;
    __syncthreads();
    if (q == 0) {
        float s = partial[0][c] + partial[1][c] + partial[2][c] + partial[3][c];
        int cnt = hi - lo;
        pooled[c] = s / (float)max(cnt, 1);
    }
    __syncthreads();
    if (tid < 64) {
        float acc = fc1_b[tid];
        const float* w = &fc1_w[(size_t)tid * 64];
        #pragma unroll
        for (int k = 0; k < 64; ++k) acc += pooled[k] * w[k];
        hmid[tid] = lrelu(acc, ACT_SLOPE);
    }
    __syncthreads();
    for (int o = tid; o < 768; o += 256) {
        float acc = fc2_b[o];
        const float* w = &fc2_w[(size_t)o * 64];
        #pragma unroll
        for (int k = 0; k < 64; ++k) acc += hmid[k] * w[k];
        out[(size_t)g * 768 + o] = acc;
    }
}

// ---------------- launch ----------------

extern "C" void kernel_launch(void* const* d_in, const int* in_sizes, int n_in,
                              void* d_out, int out_size, void* d_ws, size_t ws_size,
                              hipStream_t stream) {
    const float* x     = (const float*)d_in[0];
    const int*   ei    = (const int*)d_in[1];
    const int*   batch = (const int*)d_in[2];
    const float* w1_l  = (const float*)d_in[3];
    const float* b1_l  = (const float*)d_in[4];
    const float* w1_r  = (const float*)d_in[5];
    const float* b1_r  = (const float*)d_in[6];
    const float* att1  = (const float*)d_in[7];
    const float* bias1 = (const float*)d_in[8];
    const float* w2_l  = (const float*)d_in[9];
    const float* b2_l  = (const float*)d_in[10];
    const float* w2_r  = (const float*)d_in[11];
    const float* b2_r  = (const float*)d_in[12];
    const float* att2  = (const float*)d_in[13];
    const float* bias2 = (const float*)d_in[14];
    const float* fc1_w = (const float*)d_in[15];
    const float* fc1_b = (const float*)d_in[16];
    const float* fc2_w = (const float*)d_in[17];
    const float* fc2_b = (const float*)d_in[18];
    float* out = (float*)d_out;

    const int N = in_sizes[2];
    const int E = in_sizes[1] / 2;
    const int T = E + N;
    const int G = out_size / 768;

    char* ws = (char*)d_ws;
    size_t off = 0;
    auto alloc = [&](size_t bytes) -> void* {
        void* p = ws + off;
        off = (off + bytes + 255) & ~(size_t)255;
        return p;
    };
    int*      deg    = (int*)alloc((size_t)N * 4);
    int*      rowptr = (int*)alloc((size_t)(N + 1) * 4);
    int*      rank   = (int*)alloc((size_t)T * 4);
    int*      bsum   = (int*)alloc(1024);
    int*      boff   = (int*)alloc(1024);
    int*      adj    = (int*)alloc((size_t)T * 4);
    _Float16* h1hi   = (_Float16*)alloc((size_t)N * 128 * 2);
    _Float16* h1lo   = (_Float16*)alloc((size_t)N * 128 * 2);
    _Float16* W1h    = (_Float16*)alloc(32768 * 2);
    _Float16* W1lo   = (_Float16*)alloc(32768 * 2);
    _Float16* W2h    = (_Float16*)alloc(16384 * 2);
    _Float16* W2lo   = (_Float16*)alloc(16384 * 2);
    _Float16* buf1   = (_Float16*)alloc((size_t)N * 256 * 2);
    // lifetime aliasing: buf1 (N*512 B) dead after conv1_fused -> buf2 fp16 [N,128] (N*256 B)
    // in the first half, h2 fp32 [N,64] (N*256 B) in the second half.
    _Float16* buf2 = buf1;
    float*    h2   = (float*)((char*)buf1 + (size_t)N * 256);

    const int nbN  = (N + 255) / 256;
    const int nbT  = (T + 255) / 256;
    const int mfmG = (N / 16 + 7) / 8;          // 16-row tiles, 8 per block
    const int edgG = (N + 3) / 4;

    // ---- CSR build (deterministic: rows sorted after scatter) ----
    hipMemsetAsync(deg, 0, (size_t)N * 4, stream);
    k_count_rank<<<nbT, 256, 0, stream>>>(ei, E, N, deg, rank);
    k_scan_block<<<nbN, 256, 0, stream>>>(deg, N, rowptr + 1, bsum);
    k_scan_bsum<<<1, 256, 0, stream>>>(bsum, nbN, boff);
    k_scan_add<<<nbN, 256, 0, stream>>>(rowptr, boff, N);
    k_scatter<<<2048, 256, 0, stream>>>(ei, E, N, rowptr, rank, adj);
    k_sort_rows<<<nbN, 256, 0, stream>>>(rowptr, adj, N);

    // ---- weight encode ----
    k_encode_w<<<192, 256, 0, stream>>>(w1_l, w1_r, w2_l, w2_r, W1h, W1lo, W2h, W2lo);

    // ---- conv1 ----
    gemm_mfma<256, true><<<mfmG, 512, 0, stream>>>(x, nullptr, nullptr, N,
                                                   W1h, W1lo, b1_l, b1_r, buf1);
    conv1_fused<<<edgG, 256, 0, stream>>>(buf1, rowptr, adj, att1, bias1, h1hi, h1lo, N);

    // ---- conv2 ----
    gemm_mfma<128, false><<<mfmG, 512, 0, stream>>>(nullptr, h1hi, h1lo, N,
                                                    W2h, W2lo, b2_l, b2_r, buf2);
    conv2_fused<<<edgG, 256, 0, stream>>>(buf2, rowptr, adj, att2, bias2, h2, N);

    // ---- pool + MLP head ----
    pool_mlp<<<G, 256, 0, stream>>>(h2, batch, fc1_w, fc1_b, fc2_w, fc2_b, out, N);
}

// Round 12
// 317.466 us; speedup vs baseline: 1.2340x; 1.2340x over previous
//
#include <hip/hip_runtime.h>
#include <limits.h>

#define ATT_SLOPE 0.2f
#define ACT_SLOPE 0.01f

typedef _Float16 half8  __attribute__((ext_vector_type(8)));
typedef _Float16 half2v __attribute__((ext_vector_type(2)));
typedef float    floatx4 __attribute__((ext_vector_type(4)));

#if defined(__has_builtin)
#if __has_builtin(__builtin_amdgcn_fdot2)
#define HAVE_FDOT2 1
#endif
#endif

__device__ __forceinline__ float lrelu(float v, float s) {
    return fmaxf(v, v * s);
}

__device__ __forceinline__ half2v lrelu2(half2v m) {
    half2v t = m * (_Float16)ATT_SLOPE;
    return __builtin_elementwise_max(m, t);
}

__device__ __forceinline__ float dot2(half2v a, half2v b, float c) {
#ifdef HAVE_FDOT2
    return __builtin_amdgcn_fdot2(a, b, c, false);
#else
    return c + (float)a[0] * (float)b[0] + (float)a[1] * (float)b[1];
#endif
}

// ---------------- CSR build (edges grouped by dst, self loops appended) ----------------

// count + rank within dst (atomic order is non-deterministic; rows are sorted afterwards
// by k_sort_rows, which makes the final CSR a pure function of the input)
__global__ __launch_bounds__(256) void k_count_rank(const int* __restrict__ ei, int E, int N,
                                                    int* __restrict__ deg,
                                                    int* __restrict__ rank) {
    int i = blockIdx.x * 256 + threadIdx.x;
    int total = E + N;
    if (i >= total) return;
    int dst = (i < E) ? ei[E + i] : (i - E);
    rank[i] = atomicAdd(&deg[dst], 1);
}

__global__ __launch_bounds__(256) void k_scan_block(const int* __restrict__ deg, int n,
                                                    int* __restrict__ rp1, int* __restrict__ bsum) {
    __shared__ int s[256];
    int tid = threadIdx.x;
    int i = blockIdx.x * 256 + tid;
    s[tid] = (i < n) ? deg[i] : 0;
    __syncthreads();
    for (int off = 1; off < 256; off <<= 1) {
        int t = (tid >= off) ? s[tid - off] : 0;
        __syncthreads();
        s[tid] += t;
        __syncthreads();
    }
    if (i < n) rp1[i] = s[tid];
    if (tid == 255) bsum[blockIdx.x] = s[255];
}

__global__ __launch_bounds__(256) void k_scan_bsum(const int* __restrict__ bsum, int nb,
                                                   int* __restrict__ boff) {
    __shared__ int s[256];
    int tid = threadIdx.x;
    s[tid] = (tid < nb) ? bsum[tid] : 0;
    __syncthreads();
    for (int off = 1; off < 256; off <<= 1) {
        int t = (tid >= off) ? s[tid - off] : 0;
        __syncthreads();
        s[tid] += t;
        __syncthreads();
    }
    if (tid < nb) boff[tid] = (tid > 0) ? s[tid - 1] : 0;
}

__global__ __launch_bounds__(256) void k_scan_add(int* __restrict__ rowptr,
                                                  const int* __restrict__ boff, int n) {
    int i = blockIdx.x * 256 + threadIdx.x;
    if (i < n) rowptr[i + 1] += boff[blockIdx.x];
    if (i == 0) rowptr[0] = 0;
}

// XCD-partitioned owner-writes scatter (no cross-XCD partial-line write amplification).
__global__ __launch_bounds__(256) void k_scatter(const int* __restrict__ ei, int E, int N,
                                                 const int* __restrict__ rowptr,
                                                 const int* __restrict__ rank,
                                                 int* __restrict__ adj) {
    const int T = E + N;
    const int part = blockIdx.x & 7;
    const int rng = (N + 7) / 8;
    const int lo = part * rng, hi = min(N, lo + rng);
    const int nb = gridDim.x >> 3;
    for (int base = (int)(blockIdx.x >> 3) * 256; base < T; base += nb * 256) {
        int i = base + threadIdx.x;
        if (i >= T) continue;
        int dst = (i < E) ? ei[E + i] : (i - E);
        if (dst >= lo && dst < hi) {
            int src = (i < E) ? ei[i] : dst;
            adj[rowptr[dst] + rank[i]] = src;
        }
    }
}

// Wave-per-node bitonic sort of each CSR row (ascending). Deterministic final adj
// regardless of atomic scatter order -> bit-identical outputs on every launch.
// deg<=64: 21-stage shfl_xor network, coalesced row load/store, no divergence.
__global__ __launch_bounds__(256) void k_sort_rows(const int* __restrict__ rowptr,
                                                   int* __restrict__ adj, int n) {
    const int lane = threadIdx.x & 63, wv = threadIdx.x >> 6;
    int v = blockIdx.x * 4 + wv;
    if (v >= n) return;
    const int s = rowptr[v], e = rowptr[v + 1];
    const int deg = e - s;
    if (deg <= 1) return;
    if (deg <= 64) {
        int key = (lane < deg) ? adj[s + lane] : INT_MAX;
        #pragma unroll
        for (int k = 2; k <= 64; k <<= 1) {
            #pragma unroll
            for (int j = k >> 1; j > 0; j >>= 1) {
                int partner = __shfl_xor(key, j);
                bool up = ((lane & k) == 0) == ((lane & j) == 0);
                key = up ? min(key, partner) : max(key, partner);
            }
        }
        if (lane < deg) adj[s + lane] = key;
    } else if (lane == 0) {
        // fallback for pathological degree (not hit on this graph)
        for (int i = s + 1; i < e; ++i) {
            int key = adj[i];
            int j = i - 1;
            while (j >= s && adj[j] > key) { adj[j + 1] = adj[j]; --j; }
            adj[j + 1] = key;
        }
    }
}

// ---------------- weight hi/lo fp16 split encode (all four matrices, one launch) ------------

__global__ __launch_bounds__(256) void k_encode_w(const float* __restrict__ w1l,
                                                  const float* __restrict__ w1r,
                                                  const float* __restrict__ w2l,
                                                  const float* __restrict__ w2r,
                                                  _Float16* __restrict__ W1h,
                                                  _Float16* __restrict__ W1lo,
                                                  _Float16* __restrict__ W2h,
                                                  _Float16* __restrict__ W2lo) {
    int i = blockIdx.x * 256 + threadIdx.x;   // 0 .. 49151
    if (i >= 49152) return;
    float v;
    _Float16 *ph, *pl;
    int idx;
    if (i < 32768) {
        idx = i;
        v = (i < 16384) ? w1l[i] : w1r[i - 16384];
        ph = W1h; pl = W1lo;
    } else {
        int j = i - 32768;
        idx = j;
        v = (j < 8192) ? w2l[j] : w2r[j - 8192];
        ph = W2h; pl = W2lo;
    }
    _Float16 h = (_Float16)v;
    ph[idx] = h;
    pl[idx] = (_Float16)(v - (float)h);
}

// ---------------- MFMA split-f16 dual linear, LDS-staged W, fp16 out ----------------

template <int COUT, bool IN_F32>
__global__ __launch_bounds__(512) void gemm_mfma(const float* __restrict__ Af,
                                                 const _Float16* __restrict__ Ahi,
                                                 const _Float16* __restrict__ Alo, int n_rows,
                                                 const _Float16* __restrict__ Whi,
                                                 const _Float16* __restrict__ Wlo,
                                                 const float* __restrict__ B0,
                                                 const float* __restrict__ B1,
                                                 _Float16* __restrict__ out) {
    constexpr int NT = COUT / 16;
    constexpr int WS = 40;                      // 32 + 8 pad (16B-aligned)
    __shared__ _Float16 sWh[COUT][WS];
    __shared__ _Float16 sWl[COUT][WS];
    const int tid = threadIdx.x;
    const int lane = tid & 63, wv = tid >> 6;
    const int m = lane & 15, q = lane >> 4;
    const long row0 = ((long)blockIdx.x * 8 + wv) * 16;
    const bool active = row0 < n_rows;          // wave-uniform (n_rows % 16 == 0)
    const long arow = row0 + m;

    floatx4 acc[NT] = {};
    for (int kk = 0; kk < 128; kk += 32) {
        __syncthreads();                        // protect previous phase's reads
        for (int t = tid; t < COUT * 4; t += 512) {
            int c = t >> 2, ch = t & 3;
            *(half8*)&sWh[c][ch * 8] = *(const half8*)&Whi[(size_t)c * 128 + kk + ch * 8];
            *(half8*)&sWl[c][ch * 8] = *(const half8*)&Wlo[(size_t)c * 128 + kk + ch * 8];
        }
        __syncthreads();
        if (active) {
            half8 ah, al;
            if constexpr (IN_F32) {
                float4 a0 = *(const float4*)&Af[(size_t)arow * 128 + kk + q * 8];
                float4 a1 = *(const float4*)&Af[(size_t)arow * 128 + kk + q * 8 + 4];
                float av[8] = {a0.x, a0.y, a0.z, a0.w, a1.x, a1.y, a1.z, a1.w};
                #pragma unroll
                for (int x = 0; x < 8; ++x) {
                    ah[x] = (_Float16)av[x];
                    al[x] = (_Float16)(av[x] - (float)ah[x]);
                }
            } else {
                ah = *(const half8*)&Ahi[(size_t)arow * 128 + kk + q * 8];
                al = *(const half8*)&Alo[(size_t)arow * 128 + kk + q * 8];
            }
            #pragma unroll
            for (int nt = 0; nt < NT; ++nt) {
                half8 bh = *(const half8*)&sWh[nt * 16 + m][q * 8];
                half8 bl = *(const half8*)&sWl[nt * 16 + m][q * 8];
                acc[nt] = __builtin_amdgcn_mfma_f32_16x16x32_f16(ah, bh, acc[nt], 0, 0, 0);
                acc[nt] = __builtin_amdgcn_mfma_f32_16x16x32_f16(al, bh, acc[nt], 0, 0, 0);
                acc[nt] = __builtin_amdgcn_mfma_f32_16x16x32_f16(ah, bl, acc[nt], 0, 0, 0);
            }
        }
    }
    if (active) {
        // C/D layout: col = lane&15, row = (lane>>4)*4 + reg
        #pragma unroll
        for (int nt = 0; nt < NT; ++nt) {
            int col = nt * 16 + m;
            float b = (col < COUT / 2) ? B0[col] : B1[col - COUT / 2];
            #pragma unroll
            for (int r = 0; r < 4; ++r) {
                long grow = row0 + q * 4 + r;
                out[(size_t)grow * COUT + col] = (_Float16)(acc[nt][r] + b);
            }
        }
    }
}

// ---------------- fused GATv2 conv1 edge phase (heads=2, ch=64) ----------------
// Chunk = 16 edges, 4 lanes/edge (each 32 of 128 ch); quarter-logits via shfl_xor(16).

__global__ __launch_bounds__(256) void conv1_fused(const _Float16* __restrict__ buf,
                                                   const int* __restrict__ rowptr,
                                                   const int* __restrict__ adj,
                                                   const float* __restrict__ att,   // [128]
                                                   const float* __restrict__ bias,  // [128]
                                                   _Float16* __restrict__ h1hi,
                                                   _Float16* __restrict__ h1lo, int n) {
    __shared__ _Float16 sxl[4][16][136];   // 272B row stride, 16B-aligned
    __shared__ _Float16 sxr[4][128];
    __shared__ float    sw[4][2][16];
    __shared__ _Float16 satt[128];
    const int tid = threadIdx.x, lane = tid & 63, wv = tid >> 6;
    if (tid < 128) satt[tid] = (_Float16)att[tid];
    __syncthreads();                        // all threads reach; no block barriers after this
    int node = blockIdx.x * 4 + wv;
    if (node >= n) return;

    const int jlane = lane & 15;           // edge slot within chunk
    const int grp = lane >> 4;             // channel quarter 0..3 (0,1->head0; 2,3->head1)
    const int chq = grp * 32;
    const int head = grp >> 1;
    const int wselg = lane >> 5;           // phase-B head for channels lane*2 (0..127)
    if (lane < 16)
        *(half8*)&sxr[wv][lane * 8] = *(const half8*)&buf[(size_t)node * 256 + 128 + lane * 8];
    asm volatile("s_waitcnt lgkmcnt(0)" ::: "memory");

    const int s = rowptr[node], e = rowptr[node + 1];
    float2 accA = {0.f, 0.f}, accB = {0.f, 0.f};
    float denA = 0.f, denB = 0.f;
    for (int c0 = s; c0 < e; c0 += 16) {
        const int cnt = min(16, e - c0);
        float sacc0 = 0.f, sacc1 = 0.f;
        if (jlane < cnt) {
            int src = adj[c0 + jlane];
            const _Float16* xlp = &buf[(size_t)src * 256 + chq];
            #pragma unroll
            for (int k = 0; k < 4; ++k) {
                half8 l = *(const half8*)&xlp[k * 8];
                half8 r = *(const half8*)&sxr[wv][chq + k * 8];
                half8 a = *(const half8*)&satt[chq + k * 8];
                *(half8*)&sxl[wv][jlane][chq + k * 8] = l;
                float* sp = (k & 1) ? &sacc1 : &sacc0;
                #pragma unroll
                for (int p = 0; p < 4; ++p) {
                    half2v lp = {l[2 * p], l[2 * p + 1]};
                    half2v rp = {r[2 * p], r[2 * p + 1]};
                    half2v ap = {a[2 * p], a[2 * p + 1]};
                    *sp = dot2(lrelu2(lp + rp), ap, *sp);
                }
            }
        }
        float sacc = sacc0 + sacc1;
        float efull = sacc + __shfl_xor(sacc, 16);   // combine the two quarters of this head
        if ((grp & 1) == 0 && jlane < cnt) sw[wv][head][jlane] = __expf(efull);
        asm volatile("s_waitcnt lgkmcnt(0)" ::: "memory");
        // phase B: lane -> channels (2*lane, 2*lane+1); its head's weights; 2-way unroll
        int j = 0;
        for (; j + 1 < cnt; j += 2) {
            float w0 = sw[wv][wselg][j], w1 = sw[wv][wselg][j + 1];
            half2v v0 = *(const half2v*)&sxl[wv][j][lane * 2];
            half2v v1 = *(const half2v*)&sxl[wv][j + 1][lane * 2];
            accA.x += w0 * (float)v0[0]; accA.y += w0 * (float)v0[1]; denA += w0;
            accB.x += w1 * (float)v1[0]; accB.y += w1 * (float)v1[1]; denB += w1;
        }
        if (j < cnt) {
            float w0 = sw[wv][wselg][j];
            half2v v0 = *(const half2v*)&sxl[wv][j][lane * 2];
            accA.x += w0 * (float)v0[0]; accA.y += w0 * (float)v0[1]; denA += w0;
        }
        asm volatile("s_waitcnt lgkmcnt(0)" ::: "memory");  // drain reads before next overwrite
    }
    float inv = 1.f / (denA + denB);
    float2 b = *(const float2*)&bias[lane * 2];
    float ox = lrelu((accA.x + accB.x) * inv + b.x, ACT_SLOPE);
    float oy = lrelu((accA.y + accB.y) * inv + b.y, ACT_SLOPE);
    half2v hv, lv;
    hv[0] = (_Float16)ox; lv[0] = (_Float16)(ox - (float)hv[0]);
    hv[1] = (_Float16)oy; lv[1] = (_Float16)(oy - (float)hv[1]);
    *(half2v*)&h1hi[(size_t)node * 128 + lane * 2] = hv;
    *(half2v*)&h1lo[(size_t)node * 128 + lane * 2] = lv;
}

// ---------------- fused GATv2 conv2 edge phase (heads=1, ch=64) ----------------

__global__ __launch_bounds__(256) void conv2_fused(const _Float16* __restrict__ buf,
                                                   const int* __restrict__ rowptr,
                                                   const int* __restrict__ adj,
                                                   const float* __restrict__ att,   // [64]
                                                   const float* __restrict__ bias,  // [64]
                                                   float* __restrict__ h2, int n) {
    __shared__ _Float16 sxl[4][16][72];    // 144B row stride, 16B-aligned
    __shared__ _Float16 sxr[4][64];
    __shared__ float    sw[4][16];
    __shared__ _Float16 satt[64];
    const int tid = threadIdx.x, lane = tid & 63, wv = tid >> 6;
    if (tid < 64) satt[tid] = (_Float16)att[tid];
    __syncthreads();
    int node = blockIdx.x * 4 + wv;
    if (node >= n) return;

    const int jlane = lane & 15;
    const int grp = lane >> 4;             // channel quarter 0..3 (16 ch each)
    const int chq = grp * 16;
    if (lane < 8)
        *(half8*)&sxr[wv][lane * 8] = *(const half8*)&buf[(size_t)node * 128 + 64 + lane * 8];
    asm volatile("s_waitcnt lgkmcnt(0)" ::: "memory");

    const int s = rowptr[node], e = rowptr[node + 1];
    float accA = 0.f, accB = 0.f, denA = 0.f, denB = 0.f;
    for (int c0 = s; c0 < e; c0 += 16) {
        const int cnt = min(16, e - c0);
        float sacc = 0.f;
        if (jlane < cnt) {
            int src = adj[c0 + jlane];
            const _Float16* xlp = &buf[(size_t)src * 128 + chq];
            #pragma unroll
            for (int k = 0; k < 2; ++k) {
                half8 l = *(const half8*)&xlp[k * 8];
                half8 r = *(const half8*)&sxr[wv][chq + k * 8];
                half8 a = *(const half8*)&satt[chq + k * 8];
                *(half8*)&sxl[wv][jlane][chq + k * 8] = l;
                #pragma unroll
                for (int p = 0; p < 4; ++p) {
                    half2v lp = {l[2 * p], l[2 * p + 1]};
                    half2v rp = {r[2 * p], r[2 * p + 1]};
                    half2v ap = {a[2 * p], a[2 * p + 1]};
                    sacc = dot2(lrelu2(lp + rp), ap, sacc);
                }
            }
        }
        float s1 = sacc + __shfl_xor(sacc, 16);
        float efull = s1 + __shfl_xor(s1, 32);
        if (grp == 0 && jlane < cnt) sw[wv][jlane] = __expf(efull);
        asm volatile("s_waitcnt lgkmcnt(0)" ::: "memory");
        int j = 0;
        for (; j + 1 < cnt; j += 2) {
            float w0 = sw[wv][j], w1 = sw[wv][j + 1];
            accA += w0 * (float)sxl[wv][j][lane];     denA += w0;
            accB += w1 * (float)sxl[wv][j + 1][lane]; denB += w1;
        }
        if (j < cnt) {
            float w0 = sw[wv][j];
            accA += w0 * (float)sxl[wv][j][lane];
            denA += w0;
        }
        asm volatile("s_waitcnt lgkmcnt(0)" ::: "memory");
    }
    h2[(size_t)node * 64 + lane] = lrelu((accA + accB) / (denA + denB) + bias[lane], ACT_SLOPE);
}

// ---------------- global mean pool (batch sorted) + fc1 + lrelu + fc2 ----------------

__device__ __forceinline__ int lower_bound(const int* a, int n, int v) {
    int lo = 0, hi = n;
    while (lo < hi) { int mid = (lo + hi) >> 1; if (a[mid] < v) lo = mid + 1; else hi = mid; }
    return lo;
}

__global__ __launch_bounds__(256) void pool_mlp(const float* __restrict__ h2,   // [N,64]
                                                const int* __restrict__ batch,  // [N] sorted
                                                const float* __restrict__ fc1_w,
                                                const float* __restrict__ fc1_b,
                                                const float* __restrict__ fc2_w,
                                                const float* __restrict__ fc2_b,
                                                float* __restrict__ out, int n) {
    const int g = blockIdx.x;
    const int tid = threadIdx.x;
    const int c = tid & 63, q = tid >> 6;
    __shared__ float partial[4][64];
    __shared__ float pooled[64];
    __shared__ float hmid[64];

    int lo = lower_bound(batch, n, g);
    int hi = lower_bound(batch, n, g + 1);

    float sum = 0.f;
    for (int i = lo + q; i < hi; i += 4) sum += h2[(size_t)i * 64 + c];
    partial[q][c] = sum;
    __syncthreads();
    if (q == 0) {
        float s = partial[0][c] + partial[1][c] + partial[2][c] + partial[3][c];
        int cnt = hi - lo;
        pooled[c] = s / (float)max(cnt, 1);
    }
    __syncthreads();
    if (tid < 64) {
        float acc = fc1_b[tid];
        const float* w = &fc1_w[(size_t)tid * 64];
        #pragma unroll
        for (int k = 0; k < 64; ++k) acc += pooled[k] * w[k];
        hmid[tid] = lrelu(acc, ACT_SLOPE);
    }
    __syncthreads();
    for (int o = tid; o < 768; o += 256) {
        float acc = fc2_b[o];
        const float* w = &fc2_w[(size_t)o * 64];
        #pragma unroll
        for (int k = 0; k < 64; ++k) acc += hmid[k] * w[k];
        out[(size_t)g * 768 + o] = acc;
    }
}

// ---------------- launch ----------------

extern "C" void kernel_launch(void* const* d_in, const int* in_sizes, int n_in,
                              void* d_out, int out_size, void* d_ws, size_t ws_size,
                              hipStream_t stream) {
    const float* x     = (const float*)d_in[0];
    const int*   ei    = (const int*)d_in[1];
    const int*   batch = (const int*)d_in[2];
    const float* w1_l  = (const float*)d_in[3];
    const float* b1_l  = (const float*)d_in[4];
    const float* w1_r  = (const float*)d_in[5];
    const float* b1_r  = (const float*)d_in[6];
    const float* att1  = (const float*)d_in[7];
    const float* bias1 = (const float*)d_in[8];
    const float* w2_l  = (const float*)d_in[9];
    const float* b2_l  = (const float*)d_in[10];
    const float* w2_r  = (const float*)d_in[11];
    const float* b2_r  = (const float*)d_in[12];
    const float* att2  = (const float*)d_in[13];
    const float* bias2 = (const float*)d_in[14];
    const float* fc1_w = (const float*)d_in[15];
    const float* fc1_b = (const float*)d_in[16];
    const float* fc2_w = (const float*)d_in[17];
    const float* fc2_b = (const float*)d_in[18];
    float* out = (float*)d_out;

    const int N = in_sizes[2];
    const int E = in_sizes[1] / 2;
    const int T = E + N;
    const int G = out_size / 768;

    char* ws = (char*)d_ws;
    size_t off = 0;
    auto alloc = [&](size_t bytes) -> void* {
        void* p = ws + off;
        off = (off + bytes + 255) & ~(size_t)255;
        return p;
    };
    int*      deg    = (int*)alloc((size_t)N * 4);
    int*      rowptr = (int*)alloc((size_t)(N + 1) * 4);
    int*      rank   = (int*)alloc((size_t)T * 4);
    int*      bsum   = (int*)alloc(1024);
    int*      boff   = (int*)alloc(1024);
    int*      adj    = (int*)alloc((size_t)T * 4);
    _Float16* h1hi   = (_Float16*)alloc((size_t)N * 128 * 2);
    _Float16* h1lo   = (_Float16*)alloc((size_t)N * 128 * 2);
    _Float16* W1h    = (_Float16*)alloc(32768 * 2);
    _Float16* W1lo   = (_Float16*)alloc(32768 * 2);
    _Float16* W2h    = (_Float16*)alloc(16384 * 2);
    _Float16* W2lo   = (_Float16*)alloc(16384 * 2);
    _Float16* buf1   = (_Float16*)alloc((size_t)N * 256 * 2);
    // lifetime aliasing: buf1 (N*512 B) dead after conv1_fused -> buf2 fp16 [N,128] (N*256 B)
    // in the first half, h2 fp32 [N,64] (N*256 B) in the second half.
    _Float16* buf2 = buf1;
    float*    h2   = (float*)((char*)buf1 + (size_t)N * 256);

    const int nbN  = (N + 255) / 256;
    const int nbT  = (T + 255) / 256;
    const int mfmG = (N / 16 + 7) / 8;          // 16-row tiles, 8 per block
    const int edgG = (N + 3) / 4;

    // ---- CSR build (deterministic: rows bitonic-sorted after scatter) ----
    hipMemsetAsync(deg, 0, (size_t)N * 4, stream);
    k_count_rank<<<nbT, 256, 0, stream>>>(ei, E, N, deg, rank);
    k_scan_block<<<nbN, 256, 0, stream>>>(deg, N, rowptr + 1, bsum);
    k_scan_bsum<<<1, 256, 0, stream>>>(bsum, nbN, boff);
    k_scan_add<<<nbN, 256, 0, stream>>>(rowptr, boff, N);
    k_scatter<<<2048, 256, 0, stream>>>(ei, E, N, rowptr, rank, adj);
    k_sort_rows<<<edgG, 256, 0, stream>>>(rowptr, adj, N);

    // ---- weight encode ----
    k_encode_w<<<192, 256, 0, stream>>>(w1_l, w1_r, w2_l, w2_r, W1h, W1lo, W2h, W2lo);

    // ---- conv1 ----
    gemm_mfma<256, true><<<mfmG, 512, 0, stream>>>(x, nullptr, nullptr, N,
                                                   W1h, W1lo, b1_l, b1_r, buf1);
    conv1_fused<<<edgG, 256, 0, stream>>>(buf1, rowptr, adj, att1, bias1, h1hi, h1lo, N);

    // ---- conv2 ----
    gemm_mfma<128, false><<<mfmG, 512, 0, stream>>>(nullptr, h1hi, h1lo, N,
                                                    W2h, W2lo, b2_l, b2_r, buf2);
    conv2_fused<<<edgG, 256, 0, stream>>>(buf2, rowptr, adj, att2, bias2, h2, N);

    // ---- pool + MLP head ----
    pool_mlp<<<G, 256, 0, stream>>>(h2, batch, fc1_w, fc1_b, fc2_w, fc2_b, out, N);
}